// Round 1
// baseline (1253.897 us; speedup 1.0000x reference)
//
#include <hip/hip_runtime.h>

// Problem constants (fixed by reference setup_inputs):
// x: [B=64, C=128, H=128, W=128] fp32; keys/values: [L=50, C=128] fp32.
#define C_DIM 128
#define L_DIM 50
#define LP    52          // L padded to multiple of 4 for float4 LDS reads
#define HW    16384       // H*W
#define LOG2HW 14

__global__ __launch_bounds__(256) void slot_softmax_kernel(
    const float* __restrict__ x,
    const float* __restrict__ keys,
    const float* __restrict__ values,
    float* __restrict__ out)
{
    // Transposed LDS tiles: [c][l], padded to LP=52 cols (52*4B = 208B row, 16B-aligned)
    __shared__ __align__(16) float nkT[C_DIM][LP];
    __shared__ __align__(16) float vT[C_DIM][LP];

    const int tid = threadIdx.x;

    // ---- Stage normalized keys^T and values^T into LDS (one-time, small) ----
    if (tid < L_DIM) {
        // wave 0: normalize key row tid, scatter into column tid
        float n2 = 0.f;
        #pragma unroll 4
        for (int c = 0; c < C_DIM; ++c) {
            float k = keys[tid * C_DIM + c];
            n2 += k * k;
        }
        float rn = 1.0f / fmaxf(sqrtf(n2), 1e-12f);
        #pragma unroll 4
        for (int c = 0; c < C_DIM; ++c)
            nkT[c][tid] = keys[tid * C_DIM + c] * rn;
    } else if (tid >= 64 && tid < 64 + L_DIM) {
        // wave 1: transpose values
        int l = tid - 64;
        #pragma unroll 4
        for (int c = 0; c < C_DIM; ++c)
            vT[c][l] = values[l * C_DIM + c];
    } else if (tid >= 128 && tid < 130) {
        // zero the pad columns (50,51) so padded FMAs are harmless
        int l = L_DIM + (tid - 128);
        #pragma unroll 4
        for (int c = 0; c < C_DIM; ++c) {
            nkT[c][l] = 0.f;
            vT[c][l] = 0.f;
        }
    }
    __syncthreads();

    // ---- One thread per pixel ----
    const long long p = (long long)blockIdx.x * 256 + tid;   // global pixel id
    const int b = (int)(p >> LOG2HW);
    const int n = (int)(p & (HW - 1));
    const float* xp = x + ((long long)b << (LOG2HW + 7)) + n;   // x[b][c][n], c-stride = HW
    float*       op = out + ((long long)b << (LOG2HW + 7)) + n;

    float s[LP];
    #pragma unroll
    for (int l = 0; l < LP; ++l) s[l] = 0.f;
    float n2 = 0.f;

    // Pass 1: stream x once, accumulate 50 key-dots + ||x||^2
    #pragma unroll 2
    for (int c = 0; c < C_DIM; ++c) {
        float xc = xp[(long long)c << LOG2HW];
        n2 += xc * xc;
        const float4* row = (const float4*)&nkT[c][0];   // broadcast reads
        #pragma unroll
        for (int j = 0; j < LP / 4; ++j) {
            float4 k4 = row[j];
            s[4*j+0] += k4.x * xc;
            s[4*j+1] += k4.y * xc;
            s[4*j+2] += k4.z * xc;
            s[4*j+3] += k4.w * xc;
        }
    }

    // Softmax over L (in registers)
    float rn = 1.0f / fmaxf(sqrtf(n2), 1e-12f);
    float m = -1e30f;
    #pragma unroll
    for (int l = 0; l < L_DIM; ++l) {
        s[l] *= rn;
        m = fmaxf(m, s[l]);
    }
    float sum = 0.f;
    #pragma unroll
    for (int l = 0; l < L_DIM; ++l) {
        s[l] = __expf(s[l] - m);
        sum += s[l];
    }
    float inv = 1.0f / sum;
    #pragma unroll
    for (int l = 0; l < L_DIM; ++l) s[l] *= inv;
    s[L_DIM] = 0.f;
    s[L_DIM + 1] = 0.f;   // pad weights -> 0 so padded vT cols contribute nothing

    // Pass 2: out[b][c][n] = sum_l p[l] * values[l][c]
    #pragma unroll 2
    for (int c = 0; c < C_DIM; ++c) {
        const float4* row = (const float4*)&vT[c][0];
        float acc = 0.f;
        #pragma unroll
        for (int j = 0; j < LP / 4; ++j) {
            float4 v4 = row[j];
            acc += v4.x * s[4*j+0];
            acc += v4.y * s[4*j+1];
            acc += v4.z * s[4*j+2];
            acc += v4.w * s[4*j+3];
        }
        op[(long long)c << LOG2HW] = acc;
    }
}

extern "C" void kernel_launch(void* const* d_in, const int* in_sizes, int n_in,
                              void* d_out, int out_size, void* d_ws, size_t ws_size,
                              hipStream_t stream) {
    const float* x      = (const float*)d_in[0];
    const float* keys   = (const float*)d_in[1];
    const float* values = (const float*)d_in[2];
    float* out = (float*)d_out;

    const long long pixels = (long long)in_sizes[0] / C_DIM;  // B*H*W = 1,048,576
    const int blocks = (int)(pixels / 256);

    hipLaunchKernelGGL(slot_softmax_kernel, dim3(blocks), dim3(256), 0, stream,
                       x, keys, values, out);
}

// Round 2
// 1190.021 us; speedup vs baseline: 1.0537x; 1.0537x over previous
//
#include <hip/hip_runtime.h>

// x: [B=64, C=128, H=128, W=128] fp32; keys/values: [L=50, C=128] fp32.
#define C_DIM 128
#define L_DIM 50
#define ROWP  64          // padded row stride (floats) in ws: 256B rows
#define HW    16384
#define LOG2HW 14

typedef float f32x4 __attribute__((ext_vector_type(4)));

// ---------------- prep: normalized keys^T and values^T into ws ----------------
// ws layout: nkT [128][64] floats at ws+0 ; vT [128][64] floats at ws+8192
__global__ __launch_bounds__(256) void prep_kernel(
    const float* __restrict__ keys, const float* __restrict__ values,
    float* __restrict__ ws)
{
    __shared__ float rn[L_DIM];
    const int tid = threadIdx.x;
    if (tid < L_DIM) {
        float n2 = 0.f;
        for (int c = 0; c < C_DIM; ++c) { float k = keys[tid * C_DIM + c]; n2 += k * k; }
        rn[tid] = 1.0f / fmaxf(sqrtf(n2), 1e-12f);
    }
    __syncthreads();
    if (tid < C_DIM) {
        const int c = tid;
        float* nk = ws;                      // [c][l]
        float* vv = ws + C_DIM * ROWP;       // [c][l]
        for (int l = 0; l < ROWP; ++l) {
            nk[c * ROWP + l] = (l < L_DIM) ? keys[l * C_DIM + c] * rn[l] : 0.f;
            vv[c * ROWP + l] = (l < L_DIM) ? values[l * C_DIM + c] : 0.f;
        }
    }
}

// 13 x s_load_dwordx4 of one 52-float wave-uniform row into SGPRs + wait.
// (no LDS in this kernel, so lgkmcnt counts only these SMEM loads)
#define SLOAD52(ptr, k0,k1,k2,k3,k4,k5,k6,k7,k8,k9,k10,k11,k12)            \
    asm("s_load_dwordx4 %0, %13, 0x0\n\t"                                  \
        "s_load_dwordx4 %1, %13, 0x10\n\t"                                 \
        "s_load_dwordx4 %2, %13, 0x20\n\t"                                 \
        "s_load_dwordx4 %3, %13, 0x30\n\t"                                 \
        "s_load_dwordx4 %4, %13, 0x40\n\t"                                 \
        "s_load_dwordx4 %5, %13, 0x50\n\t"                                 \
        "s_load_dwordx4 %6, %13, 0x60\n\t"                                 \
        "s_load_dwordx4 %7, %13, 0x70\n\t"                                 \
        "s_load_dwordx4 %8, %13, 0x80\n\t"                                 \
        "s_load_dwordx4 %9, %13, 0x90\n\t"                                 \
        "s_load_dwordx4 %10, %13, 0xa0\n\t"                                \
        "s_load_dwordx4 %11, %13, 0xb0\n\t"                                \
        "s_load_dwordx4 %12, %13, 0xc0\n\t"                                \
        "s_waitcnt lgkmcnt(0)"                                             \
        : "=s"(k0), "=s"(k1), "=s"(k2), "=s"(k3), "=s"(k4), "=s"(k5),      \
          "=s"(k6), "=s"(k7), "=s"(k8), "=s"(k9), "=s"(k10), "=s"(k11),    \
          "=s"(k12)                                                        \
        : "s"(ptr))

#define DOT4(kk, b)                                                        \
    { s0[b+0] += kk[0] * xv.x;  s1[b+0] += kk[0] * xv.y;                   \
      s0[b+1] += kk[1] * xv.x;  s1[b+1] += kk[1] * xv.y;                   \
      s0[b+2] += kk[2] * xv.x;  s1[b+2] += kk[2] * xv.y;                   \
      s0[b+3] += kk[3] * xv.x;  s1[b+3] += kk[3] * xv.y; }

#define WSUM4(kk, b)                                                       \
    { acc0 += kk[0] * s0[b+0];  acc1 += kk[0] * s1[b+0];                   \
      acc0 += kk[1] * s0[b+1];  acc1 += kk[1] * s1[b+1];                   \
      acc0 += kk[2] * s0[b+2];  acc1 += kk[2] * s1[b+2];                   \
      acc0 += kk[3] * s0[b+3];  acc1 += kk[3] * s1[b+3]; }

// ---------------- main: 2 pixels per thread, keys/values from SGPRs ----------
__global__ __launch_bounds__(256) void slot_softmax_scalar(
    const float* __restrict__ x,
    const float* __restrict__ ws,
    float* __restrict__ out)
{
    const int tid = threadIdx.x;
    const long long p0 = ((long long)blockIdx.x * 256 + tid) * 2;  // 2 consecutive pixels
    const int b = (int)(p0 >> LOG2HW);
    const int n = (int)(p0 & (HW - 1));
    const float* xp = x + ((long long)b << (LOG2HW + 7)) + n;   // x[b][c][n], c-stride HW
    float*       op = out + ((long long)b << (LOG2HW + 7)) + n;

    float s0[L_DIM], s1[L_DIM];
    #pragma unroll
    for (int l = 0; l < L_DIM; ++l) { s0[l] = 0.f; s1[l] = 0.f; }
    float n20 = 0.f, n21 = 0.f;

    // ---- Pass 1: dot(x, nk_l) for all 50 slots + ||x||^2 ----
    #pragma unroll 2
    for (int c = 0; c < C_DIM; ++c) {
        const float2 xv = *reinterpret_cast<const float2*>(xp + ((long long)c << LOG2HW));
        const float* kr = ws + c * ROWP;
        f32x4 k0,k1,k2,k3,k4,k5,k6,k7,k8,k9,k10,k11,k12;
        SLOAD52(kr, k0,k1,k2,k3,k4,k5,k6,k7,k8,k9,k10,k11,k12);
        n20 += xv.x * xv.x;
        n21 += xv.y * xv.y;
        DOT4(k0, 0)  DOT4(k1, 4)  DOT4(k2, 8)  DOT4(k3, 12)
        DOT4(k4, 16) DOT4(k5, 20) DOT4(k6, 24) DOT4(k7, 28)
        DOT4(k8, 32) DOT4(k9, 36) DOT4(k10, 40) DOT4(k11, 44)
        s0[48] += k12[0] * xv.x;  s1[48] += k12[0] * xv.y;
        s0[49] += k12[1] * xv.x;  s1[49] += k12[1] * xv.y;
    }

    // ---- Softmax over 50 slots, in registers ----
    const float rn0 = 1.0f / fmaxf(sqrtf(n20), 1e-12f);
    const float rn1 = 1.0f / fmaxf(sqrtf(n21), 1e-12f);
    float m0 = -1e30f, m1 = -1e30f;
    #pragma unroll
    for (int l = 0; l < L_DIM; ++l) {
        s0[l] *= rn0;  m0 = fmaxf(m0, s0[l]);
        s1[l] *= rn1;  m1 = fmaxf(m1, s1[l]);
    }
    float sum0 = 0.f, sum1 = 0.f;
    #pragma unroll
    for (int l = 0; l < L_DIM; ++l) {
        s0[l] = __expf(s0[l] - m0);  sum0 += s0[l];
        s1[l] = __expf(s1[l] - m1);  sum1 += s1[l];
    }
    const float inv0 = 1.0f / sum0, inv1 = 1.0f / sum1;
    #pragma unroll
    for (int l = 0; l < L_DIM; ++l) { s0[l] *= inv0; s1[l] *= inv1; }

    // ---- Pass 2: out[c] = sum_l w[l] * v[l][c] ----
    const float* wsv = ws + C_DIM * ROWP;
    #pragma unroll 2
    for (int c = 0; c < C_DIM; ++c) {
        const float* vr = wsv + c * ROWP;
        f32x4 k0,k1,k2,k3,k4,k5,k6,k7,k8,k9,k10,k11,k12;
        SLOAD52(vr, k0,k1,k2,k3,k4,k5,k6,k7,k8,k9,k10,k11,k12);
        float acc0 = 0.f, acc1 = 0.f;
        WSUM4(k0, 0)  WSUM4(k1, 4)  WSUM4(k2, 8)  WSUM4(k3, 12)
        WSUM4(k4, 16) WSUM4(k5, 20) WSUM4(k6, 24) WSUM4(k7, 28)
        WSUM4(k8, 32) WSUM4(k9, 36) WSUM4(k10, 40) WSUM4(k11, 44)
        acc0 += k12[0] * s0[48];  acc1 += k12[0] * s1[48];
        acc0 += k12[1] * s0[49];  acc1 += k12[1] * s1[49];
        *reinterpret_cast<float2*>(op + ((long long)c << LOG2HW)) = make_float2(acc0, acc1);
    }
}

// ---------------- fallback (ws too small): Round-1 LDS kernel ----------------
#define LP 52
__global__ __launch_bounds__(256) void slot_softmax_lds(
    const float* __restrict__ x, const float* __restrict__ keys,
    const float* __restrict__ values, float* __restrict__ out)
{
    __shared__ __align__(16) float nkT[C_DIM][LP];
    __shared__ __align__(16) float vT[C_DIM][LP];
    const int tid = threadIdx.x;
    if (tid < L_DIM) {
        float n2 = 0.f;
        for (int c = 0; c < C_DIM; ++c) { float k = keys[tid*C_DIM+c]; n2 += k*k; }
        float rnk = 1.0f / fmaxf(sqrtf(n2), 1e-12f);
        for (int c = 0; c < C_DIM; ++c) nkT[c][tid] = keys[tid*C_DIM+c] * rnk;
    } else if (tid >= 64 && tid < 64 + L_DIM) {
        int l = tid - 64;
        for (int c = 0; c < C_DIM; ++c) vT[c][l] = values[l*C_DIM+c];
    } else if (tid >= 128 && tid < 130) {
        int l = L_DIM + (tid - 128);
        for (int c = 0; c < C_DIM; ++c) { nkT[c][l] = 0.f; vT[c][l] = 0.f; }
    }
    __syncthreads();
    const long long p = (long long)blockIdx.x * 256 + tid;
    const int b = (int)(p >> LOG2HW);
    const int n = (int)(p & (HW - 1));
    const float* xp = x + ((long long)b << (LOG2HW + 7)) + n;
    float*       op = out + ((long long)b << (LOG2HW + 7)) + n;
    float s[LP];
    #pragma unroll
    for (int l = 0; l < LP; ++l) s[l] = 0.f;
    float n2 = 0.f;
    #pragma unroll 2
    for (int c = 0; c < C_DIM; ++c) {
        float xc = xp[(long long)c << LOG2HW];
        n2 += xc * xc;
        const float4* row = (const float4*)&nkT[c][0];
        #pragma unroll
        for (int j = 0; j < LP/4; ++j) {
            float4 k4 = row[j];
            s[4*j+0] += k4.x * xc; s[4*j+1] += k4.y * xc;
            s[4*j+2] += k4.z * xc; s[4*j+3] += k4.w * xc;
        }
    }
    float rnx = 1.0f / fmaxf(sqrtf(n2), 1e-12f);
    float m = -1e30f;
    #pragma unroll
    for (int l = 0; l < L_DIM; ++l) { s[l] *= rnx; m = fmaxf(m, s[l]); }
    float sum = 0.f;
    #pragma unroll
    for (int l = 0; l < L_DIM; ++l) { s[l] = __expf(s[l] - m); sum += s[l]; }
    float inv = 1.0f / sum;
    #pragma unroll
    for (int l = 0; l < L_DIM; ++l) s[l] *= inv;
    s[L_DIM] = 0.f; s[L_DIM+1] = 0.f;
    #pragma unroll 2
    for (int c = 0; c < C_DIM; ++c) {
        const float4* row = (const float4*)&vT[c][0];
        float acc = 0.f;
        #pragma unroll
        for (int j = 0; j < LP/4; ++j) {
            float4 v4 = row[j];
            acc += v4.x*s[4*j+0] + v4.y*s[4*j+1] + v4.z*s[4*j+2] + v4.w*s[4*j+3];
        }
        op[(long long)c << LOG2HW] = acc;
    }
}

extern "C" void kernel_launch(void* const* d_in, const int* in_sizes, int n_in,
                              void* d_out, int out_size, void* d_ws, size_t ws_size,
                              hipStream_t stream) {
    const float* x      = (const float*)d_in[0];
    const float* keys   = (const float*)d_in[1];
    const float* values = (const float*)d_in[2];
    float* out = (float*)d_out;

    const long long pixels = (long long)in_sizes[0] / C_DIM;  // 1,048,576

    if (ws_size >= (size_t)(2 * C_DIM * ROWP * sizeof(float))) {
        float* ws = (float*)d_ws;
        hipLaunchKernelGGL(prep_kernel, dim3(1), dim3(256), 0, stream,
                           keys, values, ws);
        const int blocks = (int)(pixels / 512);   // 2 px/thread, 256 thr/block
        hipLaunchKernelGGL(slot_softmax_scalar, dim3(blocks), dim3(256), 0, stream,
                           x, ws, out);
    } else {
        const int blocks = (int)(pixels / 256);
        hipLaunchKernelGGL(slot_softmax_lds, dim3(blocks), dim3(256), 0, stream,
                           x, keys, values, out);
    }
}